// Round 10
// baseline (85.244 us; speedup 1.0000x reference)
//
#include <hip/hip_runtime.h>
#include <math.h>

#define N_LAYERS 6
#define NW (N_LAYERS * 4)

// POD 4-float vector (safe in LDS, no C++ ctor)
typedef float vf4 __attribute__((ext_vector_type(4)));

// Broadcast lane `lane`'s value of v to all lanes as a wave-uniform (SGPR) value.
__device__ __forceinline__ float rdl(float v, int lane) {
    return __int_as_float(__builtin_amdgcn_readlane(__float_as_int(v), lane));
}

// ---------------------------------------------------------------------------
// Single fused kernel.
// Phase P (per block, redundant, ~1.4 us): build W (16x16 complex) from the
//   24 RX gates + CNOT rings, form S_q = Re(W^dag Z_q W), contract to the
//   81-term multilinear table   out_q(x) = sum_t C_q[t] prod_p v_p[t_p],
//   v_p = {1, cos x_p, sin x_p}. Table -> LDS Cs[81] (vf4 over q).
// Phase E: each wave parks Cs in lane-partitioned VGPRs (lane l holds Cs[l]
//   and Cs[64+min(l,16)]); coefficients are broadcast per-use via v_readlane
//   -> SGPR -> v_fma(s,v,v). NO memory pipe traffic for coefficients at all.
//   Grid-stride: 512 blocks x 4 iters x M=2 samples/thread (1D arrays only;
//   R4/R7 showed 2D arrays / big unrolled M bodies fall to scratch).
// ---------------------------------------------------------------------------
__global__ __launch_bounds__(256, 2) void qfused_kernel(
    const float* __restrict__ x, const float* __restrict__ weights,
    float* __restrict__ out, int B)
{
    __shared__ float Wr[16][16], Wi[16][16];
    __shared__ float S4[4][16][16];
    __shared__ float wc[NW], ws[NW];
    __shared__ vf4 Cs[81];

    const int tid = threadIdx.x;

    // ---- P0: shared gate trig
    if (tid < NW) {
        float t = weights[tid] * 0.5f;
        wc[tid] = __cosf(t);
        ws[tid] = __sinf(t);
    }
    __syncthreads();

    // ---- P1: threads 0..15 build column `tid` of W (registers, unrolled)
    if (tid < 16) {
        float re[16], im[16];
#pragma unroll
        for (int k = 0; k < 16; ++k) { re[k] = (k == tid) ? 1.f : 0.f; im[k] = 0.f; }
#pragma unroll 1
        for (int l = 0; l < N_LAYERS; ++l) {
#pragma unroll
            for (int q = 0; q < 4; ++q) {
                const float ct = wc[l * 4 + q], sn = ws[l * 4 + q];
                const int mask = 8 >> q;
#pragma unroll
                for (int idx = 0; idx < 16; ++idx) {
                    if (idx & mask) continue;
                    const int j = idx | mask;
                    float r0 = re[idx], u0 = im[idx], r1 = re[j], u1 = im[j];
                    re[idx] = ct * r0 + sn * u1; im[idx] = ct * u0 - sn * r1;
                    re[j]   = ct * r1 + sn * u0; im[j]   = ct * u1 - sn * r0;
                }
            }
#pragma unroll
            for (int q = 0; q < 4; ++q) {
                const int cm = 8 >> q, tm = 8 >> ((q + 1) & 3);
#pragma unroll
                for (int idx = 0; idx < 16; ++idx) {
                    if ((idx & cm) && !(idx & tm)) {
                        const int j = idx | tm;
                        float t0 = re[idx]; re[idx] = re[j]; re[j] = t0;
                        float t1 = im[idx]; im[idx] = im[j]; im[j] = t1;
                    }
                }
            }
        }
#pragma unroll
        for (int k = 0; k < 16; ++k) { Wr[k][tid] = re[k]; Wi[k][tid] = im[k]; }
    }
    __syncthreads();

    // ---- P2: thread (i,j): S_q[i][j] = sum_k z_q(k) Re(W[k,i] conj(W[k,j]))
    {
        const int i = tid >> 4, j = tid & 15;
        float a0 = 0.f, a1 = 0.f, a2 = 0.f, a3 = 0.f;
#pragma unroll
        for (int k = 0; k < 16; ++k) {
            const float p = Wr[k][i] * Wr[k][j] + Wi[k][i] * Wi[k][j];
            a0 += (k & 8) ? -p : p;
            a1 += (k & 4) ? -p : p;
            a2 += (k & 2) ? -p : p;
            a3 += (k & 1) ? -p : p;
        }
        S4[0][i][j] = a0; S4[1][i][j] = a1; S4[2][i][j] = a2; S4[3][i][j] = a3;
    }
    __syncthreads();

    // ---- P3: C_q[t] = (1/16) sum_i (-1)^popc(i&zm) S_q[i][i^xm]  -> LDS
    if (tid < 81) {
        const int t1 = tid / 27, t2 = (tid / 9) % 3, t3 = (tid / 3) % 3, t4 = tid % 3;
        int zm = 0, xm = 0;
        if (t1 == 1) zm |= 8; else if (t1 == 2) xm |= 8;
        if (t2 == 1) zm |= 4; else if (t2 == 2) xm |= 4;
        if (t3 == 1) zm |= 2; else if (t3 == 2) xm |= 2;
        if (t4 == 1) zm |= 1; else if (t4 == 2) xm |= 1;
        vf4 c;
#pragma unroll
        for (int q = 0; q < 4; ++q) {
            float acc = 0.f;
#pragma unroll
            for (int i = 0; i < 16; ++i) {
                const float v = S4[q][i][i ^ xm];
                acc += (__popc(i & zm) & 1) ? -v : v;
            }
            c[q] = acc * 0.0625f;
        }
        Cs[tid] = c;
    }
    __syncthreads();

    // ---- park table in lane-partitioned VGPRs (once per thread)
    const int lane = tid & 63;
    const vf4 Areg = Cs[lane];                               // terms 0..63
    const vf4 Breg = Cs[64 + (lane < 17 ? lane : 16)];       // terms 64..80

    const float4* __restrict__ xv4 = reinterpret_cast<const float4*>(x);
    float4* __restrict__ ov4 = reinterpret_cast<float4*>(out);
    const int tbase = blockIdx.x * 256 + tid;
    const int HALF = 512 * 256;          // 131072: M=2 pair offset
    const int STRIDE = 2 * HALF;         // 262144: per-iteration stride

#pragma unroll 1
    for (int k = 0; k < 4; ++k) {
        int b0 = tbase + k * STRIDE;
        int b1 = b0 + HALF;
        b0 = (b0 < B) ? b0 : (B - 1);    // clamp (exact when B = 2^20)
        b1 = (b1 < B) ? b1 : (B - 1);
        const float4 x0 = xv4[b0];
        const float4 x1 = xv4[b1];

        float u9a[9], w9a[9], u9b[9], w9b[9];
        {
            const float c0 = __cosf(x0.x), s0 = __sinf(x0.x);
            const float c1 = __cosf(x0.y), s1 = __sinf(x0.y);
            const float c2 = __cosf(x0.z), s2 = __sinf(x0.z);
            const float c3 = __cosf(x0.w), s3 = __sinf(x0.w);
            u9a[0] = 1.f; u9a[1] = c1;      u9a[2] = s1;
            u9a[3] = c0;  u9a[4] = c0 * c1; u9a[5] = c0 * s1;
            u9a[6] = s0;  u9a[7] = s0 * c1; u9a[8] = s0 * s1;
            w9a[0] = 1.f; w9a[1] = c3;      w9a[2] = s3;
            w9a[3] = c2;  w9a[4] = c2 * c3; w9a[5] = c2 * s3;
            w9a[6] = s2;  w9a[7] = s2 * c3; w9a[8] = s2 * s3;
        }
        {
            const float c0 = __cosf(x1.x), s0 = __sinf(x1.x);
            const float c1 = __cosf(x1.y), s1 = __sinf(x1.y);
            const float c2 = __cosf(x1.z), s2 = __sinf(x1.z);
            const float c3 = __cosf(x1.w), s3 = __sinf(x1.w);
            u9b[0] = 1.f; u9b[1] = c1;      u9b[2] = s1;
            u9b[3] = c0;  u9b[4] = c0 * c1; u9b[5] = c0 * s1;
            u9b[6] = s0;  u9b[7] = s0 * c1; u9b[8] = s0 * s1;
            w9b[0] = 1.f; w9b[1] = c3;      w9b[2] = s3;
            w9b[3] = c2;  w9b[4] = c2 * c3; w9b[5] = c2 * s3;
            w9b[6] = s2;  w9b[7] = s2 * c3; w9b[8] = s2 * s3;
        }

        float4 oa = make_float4(0.f, 0.f, 0.f, 0.f);
        float4 ob = make_float4(0.f, 0.f, 0.f, 0.f);
#pragma unroll
        for (int i = 0; i < 9; ++i) {
            float4 ta = make_float4(0.f, 0.f, 0.f, 0.f);
            float4 tb = make_float4(0.f, 0.f, 0.f, 0.f);
#pragma unroll
            for (int j = 0; j < 9; ++j) {
                const int t = i * 9 + j;
                float cx, cy, cz, cw;
                if (t < 64) {
                    cx = rdl(Areg.x, t); cy = rdl(Areg.y, t);
                    cz = rdl(Areg.z, t); cw = rdl(Areg.w, t);
                } else {
                    cx = rdl(Breg.x, t - 64); cy = rdl(Breg.y, t - 64);
                    cz = rdl(Breg.z, t - 64); cw = rdl(Breg.w, t - 64);
                }
                const float wa = w9a[j], wb = w9b[j];
                ta.x = fmaf(cx, wa, ta.x); ta.y = fmaf(cy, wa, ta.y);
                ta.z = fmaf(cz, wa, ta.z); ta.w = fmaf(cw, wa, ta.w);
                tb.x = fmaf(cx, wb, tb.x); tb.y = fmaf(cy, wb, tb.y);
                tb.z = fmaf(cz, wb, tb.z); tb.w = fmaf(cw, wb, tb.w);
            }
            const float ua = u9a[i], ub = u9b[i];
            oa.x = fmaf(ta.x, ua, oa.x); oa.y = fmaf(ta.y, ua, oa.y);
            oa.z = fmaf(ta.z, ua, oa.z); oa.w = fmaf(ta.w, ua, oa.w);
            ob.x = fmaf(tb.x, ub, ob.x); ob.y = fmaf(tb.y, ub, ob.y);
            ob.z = fmaf(tb.z, ub, ob.z); ob.w = fmaf(tb.w, ub, ob.w);
        }

        ov4[b0] = oa;
        ov4[b1] = ob;
    }
}

extern "C" void kernel_launch(void* const* d_in, const int* in_sizes, int n_in,
                              void* d_out, int out_size, void* d_ws, size_t ws_size,
                              hipStream_t stream) {
    const float* x = (const float*)d_in[0];
    const float* weights = (const float*)d_in[1];
    float* out = (float*)d_out;
    const int B = in_sizes[0] / 4;

    // 512 blocks x 256 threads x (4 iters x 2 samples) = 2^20 samples
    qfused_kernel<<<512, 256, 0, stream>>>(x, weights, out, B);
}